// Round 5
// baseline (460.629 us; speedup 1.0000x reference)
//
#include <hip/hip_runtime.h>
#include <math.h>

// Problem constants (match reference)
constexpr int N   = 1024;
constexpr int D   = 128;
constexpr int S   = 200;
constexpr int D2  = D / 2;            // float2 elements per row
constexpr int ND2 = N * D2;           // per-step noise stride in float2
constexpr int CHAIN_BLOCKS = (N * D2) / 256;   // 256 blocks cover all chains
constexpr int SEG = 8;                // k-segments, each block owns 25 steps
constexpr int L   = S / SEG;          // 25
constexpr int PF2 = 5;                // prefetch batch (divides L)
constexpr int PF  = 8;                // fallback kernel prefetch

// clang builtin vector types
typedef float  f2 __attribute__((ext_vector_type(2)));
typedef float  f4 __attribute__((ext_vector_type(4)));
typedef double d2 __attribute__((ext_vector_type(2)));

// Workspace layout (units of d2 = 16 B):
//   PT [S][D2]  : P_k   = prod_{i<=k} (1 - g_i/v)          (per k, per d-pair)
//   QT [S][D2]  : Q_k   = sum_{i<=k} (g_i/v)*m / P_i
//   CT [S][D2]  : c_k   = sqrt(2 g_k) / P_k
//   PART [SEG][ND2] : per-segment noise partial sums
constexpr size_t PT_OFF   = 0;
constexpr size_t QT_OFF   = (size_t)S * D2;
constexpr size_t CT_OFF   = (size_t)2 * S * D2;
constexpr size_t PART_OFF = (size_t)3 * S * D2;
constexpr size_t WS_D2    = PART_OFF + (size_t)SEG * ND2;   // ~9.0 MB

// ---------------------------------------------------------------------------
// Tiny serial precompute of the per-(k,d) closed-form tables in f64.
// x_k = a_k x_{k-1} + c_k + s_k z_k  with a=1-g/v, c=(g/v)m, s=sqrt(2g)
//  =>  x_k = P_k * ( x0 + Q_k + sum_{j<=k} (s_j/P_j) z_j )
// ---------------------------------------------------------------------------
__global__ __launch_bounds__(64, 1) void precompute_kernel(
    const f2* __restrict__ var,
    const f2* __restrict__ mean,
    const float* __restrict__ gammas,
    d2* __restrict__ ws)
{
    const int dp = threadIdx.x;           // 0..63
    d2* PT = ws + PT_OFF;
    d2* QT = ws + QT_OFF;
    d2* CT = ws + CT_OFF;

    const f2 vv = var[dp];
    const f2 mm = mean[dp];
    const double vx = vv.x, vy = vv.y, mx = mm.x, my = mm.y;
    double Px = 1.0, Py = 1.0, Qx = 0.0, Qy = 0.0;

    for (int j = 0; j < S; ++j) {
        const double g  = (double)gammas[j];
        Px *= (1.0 - g / vx);
        Py *= (1.0 - g / vy);
        const double rx = 1.0 / Px, ry = 1.0 / Py;
        const double s  = sqrt(2.0 * g);
        d2 ct; ct.x = s * rx;           ct.y = s * ry;           CT[(size_t)j * D2 + dp] = ct;
        Qx += (g / vx) * mx * rx;
        Qy += (g / vy) * my * ry;
        d2 pt; pt.x = Px; pt.y = Py;    PT[(size_t)j * D2 + dp] = pt;
        d2 qt; qt.x = Qx; qt.y = Qy;    QT[(size_t)j * D2 + dp] = qt;
    }
}

// ---------------------------------------------------------------------------
// Phase A: per (segment, chain) partial noise sums, f64. Fully parallel
// streaming read of the 100 MB noise (cached -> warms L3 for phase B).
// ---------------------------------------------------------------------------
__global__ __launch_bounds__(256, 4) void partial_kernel(
    const f2* __restrict__ noise,   // [S][N][D2]
    d2* __restrict__ ws)
{
    const int seg = blockIdx.x / CHAIN_BLOCKS;
    const int rb  = blockIdx.x % CHAIN_BLOCKS;
    const int k0  = seg * L;
    const int idx = rb * 256 + threadIdx.x;          // 0 .. ND2-1
    const int dp  = idx & 63;

    const d2* CT = ws + CT_OFF;
    const f2* zp = noise + (size_t)k0 * ND2 + idx;
    const d2* ct = CT + (size_t)k0 * D2 + dp;

    d2 sig; sig.x = 0.0; sig.y = 0.0;

    f2 zb[PF2]; d2 cb[PF2];
    #pragma unroll
    for (int i = 0; i < PF2; ++i) {
        zb[i] = zp[(size_t)i * ND2];
        cb[i] = ct[(size_t)i * D2];
    }

    #pragma unroll 1
    for (int kb = 0; kb < L; kb += PF2) {
        f2 zn[PF2]; d2 cn[PF2];
        const bool more = (kb + PF2) < L;
        #pragma unroll
        for (int i = 0; i < PF2; ++i) {
            zn[i] = more ? zp[(size_t)(kb + PF2 + i) * ND2] : zb[i];
            cn[i] = more ? ct[(size_t)(kb + PF2 + i) * D2]  : cb[i];
        }
        #pragma unroll
        for (int i = 0; i < PF2; ++i) {
            sig.x = fma(cb[i].x, (double)zb[i].x, sig.x);
            sig.y = fma(cb[i].y, (double)zb[i].y, sig.y);
        }
        #pragma unroll
        for (int i = 0; i < PF2; ++i) { zb[i] = zn[i]; cb[i] = cn[i]; }
    }

    ws[PART_OFF + (size_t)seg * ND2 + idx] = sig;
}

// ---------------------------------------------------------------------------
// Phase B: each segment block reconstructs its boundary x from the closed
// form, then replays its 25 steps with the ORIGINAL fp32 fmaf sequence
// (bit-compatible within the segment). Plus 1024 y/steps writer blocks.
// ---------------------------------------------------------------------------
__global__ __launch_bounds__(256, 4) void emit_kernel(
    const f2* __restrict__ x0,
    const f4* __restrict__ y0,
    const f2* __restrict__ mean,
    const f2* __restrict__ var,
    const float* __restrict__ gammas,
    const f2* __restrict__ noise,   // [S][N][D2]
    const d2* __restrict__ ws,
    f2* __restrict__ x_tot,         // [N][S][D2]
    f4* __restrict__ y_tot,         // [N][S][D/4]
    f2* __restrict__ outp,          // [N][S][D2]
    float* __restrict__ steps)      // [N][S]
{
    if (blockIdx.x >= SEG * CHAIN_BLOCKS) {
        // ---------- y / steps writer: one block per sample n ----------
        const int n   = blockIdx.x - SEG * CHAIN_BLOCKS;
        const int t   = threadIdx.x;
        const int col = t & 31;
        const int r0  = t >> 5;
        const f4  yv  = y0[(size_t)n * 32 + col];
        f4* yq = y_tot + (size_t)n * (S * 32);
        #pragma unroll
        for (int j = 0; j < S / 8; ++j) {
            const int k = r0 + j * 8;
            __builtin_nontemporal_store(yv, &yq[(size_t)k * 32 + col]);
        }
        if (t < S) steps[(size_t)n * S + t] = (float)t;
        return;
    }

    __shared__ float sg[L];
    __shared__ float ss[L];
    const int seg = blockIdx.x / CHAIN_BLOCKS;
    const int rb  = blockIdx.x % CHAIN_BLOCKS;
    const int k0  = seg * L;
    if (threadIdx.x < L) {
        float g = gammas[k0 + threadIdx.x];
        sg[threadIdx.x] = g;
        ss[threadIdx.x] = sqrtf(2.0f * g);
    }
    __syncthreads();

    const int idx = rb * 256 + threadIdx.x;          // 0 .. ND2-1
    const int n   = idx >> 6;
    const int dp  = idx & 63;

    const f2 m  = mean[dp];
    const f2 v  = var[dp];
    const float ivx = 1.0f / v.x;
    const float ivy = 1.0f / v.y;

    // ----- boundary x_{k0-1} from closed form (f64) -----
    f2 x;
    if (seg == 0) {
        x = x0[idx];
    } else {
        d2 W; W.x = 0.0; W.y = 0.0;
        #pragma unroll 1
        for (int s2 = 0; s2 < seg; ++s2) {
            const d2 p = ws[PART_OFF + (size_t)s2 * ND2 + idx];
            W.x += p.x; W.y += p.y;
        }
        const d2 P = ws[PT_OFF + (size_t)(k0 - 1) * D2 + dp];
        const d2 Q = ws[QT_OFF + (size_t)(k0 - 1) * D2 + dp];
        const f2 xi = x0[idx];
        x.x = (float)(P.x * ((double)xi.x + Q.x + W.x));
        x.y = (float)(P.y * ((double)xi.y + Q.y + W.y));
    }

    // ----- replay segment: steps k0 .. k0+L-1, original fp32 sequence -----
    const f2* zq = noise + (size_t)k0 * ND2 + idx;
    f2* xq = x_tot + (size_t)n * (S * D2) + (size_t)k0 * D2 + dp;
    f2* oq = outp  + (size_t)n * (S * D2) + (size_t)k0 * D2 + dp;

    f2 zb[PF2];
    #pragma unroll
    for (int i = 0; i < PF2; ++i) zb[i] = zq[(size_t)i * ND2];

    #pragma unroll 1
    for (int kb = 0; kb < L; kb += PF2) {
        f2 zn[PF2];
        const bool more = (k0 + kb + PF2) < S;
        #pragma unroll
        for (int i = 0; i < PF2; ++i)
            zn[i] = more ? zq[(size_t)(kb + PF2 + i) * ND2] : zb[i];
        #pragma unroll
        for (int i = 0; i < PF2; ++i) {
            const int kk = kb + i;
            const float g = sg[kk];
            const float s = ss[kk];
            const float gx = g * ivx;
            const float gy = g * ivy;

            const float tox = fmaf(-gx, x.x - m.x, x.x);
            const float toy = fmaf(-gy, x.y - m.y, x.y);
            x.x = fmaf(s, zb[i].x, tox);
            x.y = fmaf(s, zb[i].y, toy);
            const float tnx = fmaf(-gx, x.x - m.x, x.x);
            const float tny = fmaf(-gy, x.y - m.y, x.y);

            f2 o;
            o.x = tox - tnx;
            o.y = toy - tny;

            __builtin_nontemporal_store(x, &xq[(size_t)kk * D2]);
            __builtin_nontemporal_store(o, &oq[(size_t)kk * D2]);
        }
        #pragma unroll
        for (int i = 0; i < PF2; ++i) zb[i] = zn[i];
    }
}

// ---------------------------------------------------------------------------
// Fallback: round-2 single-phase kernel (used only if ws_size is too small).
// ---------------------------------------------------------------------------
__global__ __launch_bounds__(256, 4) void langevin_kernel(
    const f2* __restrict__ x0,
    const f4* __restrict__ y0,
    const f2* __restrict__ mean,
    const f2* __restrict__ var,
    const float* __restrict__ gammas,
    const f2* __restrict__ noise,
    f2* __restrict__ x_tot,
    f4* __restrict__ y_tot,
    f2* __restrict__ outp,
    float* __restrict__ steps)
{
    if (blockIdx.x >= CHAIN_BLOCKS) {
        const int n   = blockIdx.x - CHAIN_BLOCKS;
        const int t   = threadIdx.x;
        const int col = t & 31;
        const int r0  = t >> 5;
        const f4  yv  = y0[(size_t)n * 32 + col];
        f4* yq = y_tot + (size_t)n * (S * 32);
        #pragma unroll
        for (int j = 0; j < S / 8; ++j) {
            const int k = r0 + j * 8;
            __builtin_nontemporal_store(yv, &yq[(size_t)k * 32 + col]);
        }
        if (t < S) steps[(size_t)n * S + t] = (float)t;
        return;
    }

    __shared__ float sg[S];
    __shared__ float ss[S];
    for (int i = threadIdx.x; i < S; i += 256) {
        float g = gammas[i];
        sg[i] = g;
        ss[i] = sqrtf(2.0f * g);
    }
    __syncthreads();

    const int idx = blockIdx.x * 256 + threadIdx.x;
    const int n   = idx >> 6;
    const int dp  = idx & 63;

    f2 x        = x0[idx];
    const f2 m  = mean[dp];
    const f2 v  = var[dp];
    const float ivx = 1.0f / v.x;
    const float ivy = 1.0f / v.y;

    const f2* zp = noise + idx;
    f2* xq = x_tot + (size_t)n * (S * D2) + dp;
    f2* oq = outp  + (size_t)n * (S * D2) + dp;

    f2 zb[PF];
    #pragma unroll
    for (int i = 0; i < PF; ++i)
        zb[i] = __builtin_nontemporal_load(&zp[(size_t)i * ND2]);

    #pragma unroll 1
    for (int kb = 0; kb < S; kb += PF) {
        f2 zn[PF];
        if (kb + PF < S) {
            #pragma unroll
            for (int i = 0; i < PF; ++i)
                zn[i] = __builtin_nontemporal_load(&zp[(size_t)(kb + PF + i) * ND2]);
        }
        #pragma unroll
        for (int i = 0; i < PF; ++i) {
            const int k = kb + i;
            const float g = sg[k];
            const float s = ss[k];
            const float gx = g * ivx;
            const float gy = g * ivy;

            const float tox = fmaf(-gx, x.x - m.x, x.x);
            const float toy = fmaf(-gy, x.y - m.y, x.y);
            x.x = fmaf(s, zb[i].x, tox);
            x.y = fmaf(s, zb[i].y, toy);
            const float tnx = fmaf(-gx, x.x - m.x, x.x);
            const float tny = fmaf(-gy, x.y - m.y, x.y);

            f2 o;
            o.x = tox - tnx;
            o.y = toy - tny;

            __builtin_nontemporal_store(x, &xq[(size_t)k * D2]);
            __builtin_nontemporal_store(o, &oq[(size_t)k * D2]);
        }
        #pragma unroll
        for (int i = 0; i < PF; ++i) zb[i] = zn[i];
    }
}

extern "C" void kernel_launch(void* const* d_in, const int* in_sizes, int n_in,
                              void* d_out, int out_size, void* d_ws, size_t ws_size,
                              hipStream_t stream)
{
    const float* x0     = (const float*)d_in[0];
    const float* y0     = (const float*)d_in[1];
    const float* mean   = (const float*)d_in[2];
    const float* var    = (const float*)d_in[3];
    const float* gammas = (const float*)d_in[4];
    const float* noise  = (const float*)d_in[5];

    float* x_tot = (float*)d_out;                       // N*S*D
    float* y_tot = x_tot + (size_t)N * S * D;           // N*S*D
    float* outp  = y_tot + (size_t)N * S * D;           // N*S*D
    float* steps = outp  + (size_t)N * S * D;           // N*S

    const size_t need = WS_D2 * sizeof(d2);             // ~9.0 MB
    if (d_ws != nullptr && ws_size >= need) {
        d2* ws = (d2*)d_ws;
        precompute_kernel<<<1, 64, 0, stream>>>(
            (const f2*)var, (const f2*)mean, gammas, ws);
        partial_kernel<<<SEG * CHAIN_BLOCKS, 256, 0, stream>>>(
            (const f2*)noise, ws);
        emit_kernel<<<SEG * CHAIN_BLOCKS + N, 256, 0, stream>>>(
            (const f2*)x0, (const f4*)y0, (const f2*)mean, (const f2*)var,
            gammas, (const f2*)noise, ws,
            (f2*)x_tot, (f4*)y_tot, (f2*)outp, steps);
    } else {
        langevin_kernel<<<CHAIN_BLOCKS + N, 256, 0, stream>>>(
            (const f2*)x0, (const f4*)y0, (const f2*)mean, (const f2*)var,
            gammas, (const f2*)noise,
            (f2*)x_tot, (f4*)y_tot, (f2*)outp, steps);
    }
}

// Round 6
// 396.825 us; speedup vs baseline: 1.1608x; 1.1608x over previous
//
#include <hip/hip_runtime.h>
#include <math.h>

// Problem constants (match reference)
constexpr int N   = 1024;
constexpr int D   = 128;
constexpr int S   = 200;
constexpr int D2  = D / 2;            // float2 elements per row
constexpr int ND2 = N * D2;           // per-step noise stride in float2
constexpr int CHAIN_BLOCKS = (N * D2) / 256;   // 256 blocks own the recurrence
constexpr int PF  = 8;                // noise prefetch depth (S % PF == 0)

// clang builtin vector types — required by __builtin_nontemporal_{load,store}
// (HIP_vector_type float2/float4 are classes and are rejected).
typedef float f2 __attribute__((ext_vector_type(2)));
typedef float f4 __attribute__((ext_vector_type(4)));

// Grid = 256 chain blocks + 1024 y/steps writer blocks (one per sample n).
// Chain blocks run the sequential 200-step recurrence (x, out only).
// Writer blocks stream the step-invariant y broadcast + steps ramp with
// float4 stores.
// NOTE (session journal): the timed harness region contains two ~198 µs
// 1.26 GB poison fills; total ≈ 198 + max(198, T_kernel). This kernel's
// T ≤ 198 µs, so it sits at the ~396 µs harness floor (measured 396.3).
__global__ __launch_bounds__(256, 4) void langevin_kernel(
    const f2* __restrict__ x0,
    const f4* __restrict__ y0,
    const f2* __restrict__ mean,
    const f2* __restrict__ var,
    const float* __restrict__ gammas,
    const f2* __restrict__ noise,   // [S][N][D2]
    f2* __restrict__ x_tot,         // [N][S][D2]
    f4* __restrict__ y_tot,         // [N][S][D/4]
    f2* __restrict__ outp,          // [N][S][D2]
    float* __restrict__ steps)      // [N][S]
{
    if (blockIdx.x >= CHAIN_BLOCKS) {
        // ---------- y / steps writer: one block per sample n ----------
        const int n   = blockIdx.x - CHAIN_BLOCKS;
        const int t   = threadIdx.x;
        const int col = t & 31;         // float4 column 0..31  (32*4 = 128 floats)
        const int r0  = t >> 5;         // row-group 0..7
        const f4  yv  = y0[(size_t)n * 32 + col];
        f4* yq = y_tot + (size_t)n * (S * 32);
        #pragma unroll
        for (int j = 0; j < S / 8; ++j) {
            const int k = r0 + j * 8;   // wave covers 2 rows = 1 KiB contiguous
            __builtin_nontemporal_store(yv, &yq[(size_t)k * 32 + col]);
        }
        if (t < S) steps[(size_t)n * S + t] = (float)t;
        return;
    }

    // ---------- recurrence chains: one thread per (n, d-pair) ----------
    __shared__ float sg[S];
    __shared__ float ss[S];
    for (int i = threadIdx.x; i < S; i += 256) {
        float g = gammas[i];
        sg[i] = g;
        ss[i] = sqrtf(2.0f * g);
    }
    __syncthreads();

    const int idx = blockIdx.x * 256 + threadIdx.x;  // 0 .. N*D2-1
    const int n   = idx >> 6;                        // idx / D2
    const int dp  = idx & 63;                        // idx % D2

    f2 x        = x0[idx];
    const f2 m  = mean[dp];
    const f2 v  = var[dp];
    const float ivx = 1.0f / v.x;
    const float ivy = 1.0f / v.y;

    const f2* zp = noise + idx;                      // + k*ND2 per step
    f2* xq = x_tot + (size_t)n * (S * D2) + dp;      // + k*D2 per step
    f2* oq = outp  + (size_t)n * (S * D2) + dp;

    // 8-deep software pipeline on the noise stream: 8 loads (4 KiB/wave)
    // in flight while the dependent FMA chain + stores run. All indices
    // compile-time constant -> registers, no scratch.
    f2 zb[PF];
    #pragma unroll
    for (int i = 0; i < PF; ++i)
        zb[i] = __builtin_nontemporal_load(&zp[(size_t)i * ND2]);

    #pragma unroll 1
    for (int kb = 0; kb < S; kb += PF) {
        f2 zn[PF];
        if (kb + PF < S) {
            #pragma unroll
            for (int i = 0; i < PF; ++i)
                zn[i] = __builtin_nontemporal_load(&zp[(size_t)(kb + PF + i) * ND2]);
        }
        #pragma unroll
        for (int i = 0; i < PF; ++i) {
            const int k = kb + i;
            const float g = sg[k];
            const float s = ss[k];
            const float gx = g * ivx;
            const float gy = g * ivy;

            // t_old = x - (g/v)*(x-m)
            const float tox = fmaf(-gx, x.x - m.x, x.x);
            const float toy = fmaf(-gy, x.y - m.y, x.y);
            // x_new = t_old + sqrt(2g)*z
            x.x = fmaf(s, zb[i].x, tox);
            x.y = fmaf(s, zb[i].y, toy);
            // t_new = x_new - (g/v)*(x_new-m)
            const float tnx = fmaf(-gx, x.x - m.x, x.x);
            const float tny = fmaf(-gy, x.y - m.y, x.y);

            f2 o;
            o.x = tox - tnx;
            o.y = toy - tny;

            __builtin_nontemporal_store(x, &xq[(size_t)k * D2]);
            __builtin_nontemporal_store(o, &oq[(size_t)k * D2]);
        }
        #pragma unroll
        for (int i = 0; i < PF; ++i) zb[i] = zn[i];
    }
}

extern "C" void kernel_launch(void* const* d_in, const int* in_sizes, int n_in,
                              void* d_out, int out_size, void* d_ws, size_t ws_size,
                              hipStream_t stream)
{
    const float* x0     = (const float*)d_in[0];
    const float* y0     = (const float*)d_in[1];
    const float* mean   = (const float*)d_in[2];
    const float* var    = (const float*)d_in[3];
    const float* gammas = (const float*)d_in[4];
    const float* noise  = (const float*)d_in[5];

    float* x_tot = (float*)d_out;                       // N*S*D
    float* y_tot = x_tot + (size_t)N * S * D;           // N*S*D
    float* outp  = y_tot + (size_t)N * S * D;           // N*S*D
    float* steps = outp  + (size_t)N * S * D;           // N*S

    dim3 grid(CHAIN_BLOCKS + N);   // 256 chain blocks + 1024 y-writer blocks
    dim3 block(256);
    langevin_kernel<<<grid, block, 0, stream>>>(
        (const f2*)x0, (const f4*)y0, (const f2*)mean,
        (const f2*)var, gammas, (const f2*)noise,
        (f2*)x_tot, (f4*)y_tot, (f2*)outp, steps);
}

// Round 7
// 395.406 us; speedup vs baseline: 1.1650x; 1.0036x over previous
//
#include <hip/hip_runtime.h>
#include <math.h>

// Problem constants (match reference)
constexpr int N   = 1024;
constexpr int D   = 128;
constexpr int S   = 200;
constexpr int ND  = N * D;             // per-step noise stride in floats
constexpr int CHAIN_BLOCKS = ND / 256; // 512 blocks: one SCALAR chain/thread
constexpr int PF  = 10;                // noise prefetch depth (S % PF == 0)

// clang builtin vector type for the y-writer (nontemporal builtins reject
// HIP_vector_type classes).
typedef float f4 __attribute__((ext_vector_type(4)));

// Grid = 512 chain blocks + 1024 y/steps writer blocks.
// CHANGE vs round 2: one thread per (n,d) SCALAR instead of per float2 pair.
// 131072 threads -> 512 blocks -> 2 blocks/CU -> 2 waves/SIMD (was 1).
// Same FLOPs, same bytes, same fmaf sequence per element (bitwise-identical
// output); purely doubles latency hiding for the HBM streams.
// Session model: dur_us ~= poison_fill(~198us) + T_kernel (additive; overlap
// model ruled out by BW-sharing arithmetic). Round-2 T ~= 196us at 1
// wave/SIMD; this targets T ~= 100-130us.
__global__ __launch_bounds__(256, 4) void langevin_kernel(
    const float* __restrict__ x0,
    const f4*    __restrict__ y0,
    const float* __restrict__ mean,
    const float* __restrict__ var,
    const float* __restrict__ gammas,
    const float* __restrict__ noise,   // [S][N][D]
    float* __restrict__ x_tot,         // [N][S][D]
    f4*    __restrict__ y_tot,         // [N][S][D/4]
    float* __restrict__ outp,          // [N][S][D]
    float* __restrict__ steps)         // [N][S]
{
    if (blockIdx.x >= CHAIN_BLOCKS) {
        // ---------- y / steps writer: one block per sample n ----------
        const int n   = blockIdx.x - CHAIN_BLOCKS;
        const int t   = threadIdx.x;
        const int col = t & 31;         // float4 column 0..31 (32*4 = 128 floats)
        const int r0  = t >> 5;         // row-group 0..7
        const f4  yv  = y0[(size_t)n * 32 + col];
        f4* yq = y_tot + (size_t)n * (S * 32);
        #pragma unroll
        for (int j = 0; j < S / 8; ++j) {
            const int k = r0 + j * 8;   // wave covers 2 rows = 1 KiB contiguous
            __builtin_nontemporal_store(yv, &yq[(size_t)k * 32 + col]);
        }
        if (t < S) steps[(size_t)n * S + t] = (float)t;
        return;
    }

    // ---------- recurrence chains: one thread per (n, d) scalar ----------
    __shared__ float sg[S];
    __shared__ float ss[S];
    for (int i = threadIdx.x; i < S; i += 256) {
        float g = gammas[i];
        sg[i] = g;
        ss[i] = sqrtf(2.0f * g);
    }
    __syncthreads();

    const int idx = blockIdx.x * 256 + threadIdx.x;  // 0 .. N*D-1
    const int n   = idx >> 7;                        // idx / D
    const int d   = idx & 127;                       // idx % D

    float x        = x0[idx];
    const float m  = mean[d];
    const float iv = 1.0f / var[d];

    const float* zp = noise + idx;                   // + k*ND per step
    float* xq = x_tot + (size_t)n * (S * D) + d;     // + k*D per step
    float* oq = outp  + (size_t)n * (S * D) + d;

    // PF-deep software pipeline on the noise stream: 10 loads (2.5 KB/wave,
    // 20 KB/CU at 8 waves) in flight while the dependent FMA chain + stores
    // run. All indices compile-time constant -> registers, no scratch.
    float zb[PF];
    #pragma unroll
    for (int i = 0; i < PF; ++i)
        zb[i] = __builtin_nontemporal_load(&zp[(size_t)i * ND]);

    #pragma unroll 1
    for (int kb = 0; kb < S; kb += PF) {
        float zn[PF];
        if (kb + PF < S) {
            #pragma unroll
            for (int i = 0; i < PF; ++i)
                zn[i] = __builtin_nontemporal_load(&zp[(size_t)(kb + PF + i) * ND]);
        }
        #pragma unroll
        for (int i = 0; i < PF; ++i) {
            const int k = kb + i;
            const float g  = sg[k];
            const float s  = ss[k];
            const float gx = g * iv;

            // t_old = x - (g/v)*(x-m)
            const float to = fmaf(-gx, x - m, x);
            // x_new = t_old + sqrt(2g)*z
            x = fmaf(s, zb[i], to);
            // t_new = x_new - (g/v)*(x_new-m)
            const float tn = fmaf(-gx, x - m, x);

            __builtin_nontemporal_store(x, &xq[(size_t)k * D]);
            __builtin_nontemporal_store(to - tn, &oq[(size_t)k * D]);
        }
        #pragma unroll
        for (int i = 0; i < PF; ++i) zb[i] = zn[i];
    }
}

extern "C" void kernel_launch(void* const* d_in, const int* in_sizes, int n_in,
                              void* d_out, int out_size, void* d_ws, size_t ws_size,
                              hipStream_t stream)
{
    const float* x0     = (const float*)d_in[0];
    const float* y0     = (const float*)d_in[1];
    const float* mean   = (const float*)d_in[2];
    const float* var    = (const float*)d_in[3];
    const float* gammas = (const float*)d_in[4];
    const float* noise  = (const float*)d_in[5];

    float* x_tot = (float*)d_out;                       // N*S*D
    float* y_tot = x_tot + (size_t)N * S * D;           // N*S*D
    float* outp  = y_tot + (size_t)N * S * D;           // N*S*D
    float* steps = outp  + (size_t)N * S * D;           // N*S

    dim3 grid(CHAIN_BLOCKS + N);   // 512 chain blocks + 1024 y-writer blocks
    dim3 block(256);
    langevin_kernel<<<grid, block, 0, stream>>>(
        x0, (const f4*)y0, mean, var, gammas, noise,
        x_tot, (f4*)y_tot, outp, steps);
}